// Round 13
// baseline (119.110 us; speedup 1.0000x reference)
//
#include <hip/hip_runtime.h>
#include <hip/hip_bf16.h>

typedef unsigned int u32;
typedef unsigned short u16;
typedef __attribute__((ext_vector_type(8))) __bf16 bf16x8;
typedef __attribute__((ext_vector_type(16))) float f32x16;
typedef __attribute__((ext_vector_type(2))) unsigned int u32x2;

// log2(e)/sqrt(32): folds exp->exp2 and 1/sqrt(rank) into Q.
#define QSCALE 0.25505418f
#define MFMA __builtin_amdgcn_mfma_f32_32x32x16_bf16

// Fragment-major (FM) layout for a 32-row x 16-col bf16 MFMA operand tile:
// lane l holds row (l&31), cols (l>>5)*8 + 0..7 -> flat slot = lane*8 + e.
// A 32x32 operand = 2 kchunks (512 u16). All global operands stored FM so
// hot loops load "base + l*8": coalesced 1KB/wave bursts (r7/r10 ladder).

static __device__ __forceinline__ u16 f2b(float f) {
  __hip_bfloat16 h = __float2bfloat16(f);
  return *reinterpret_cast<u16*>(&h);
}
static __device__ __forceinline__ u32 cvtpk(float lo, float hi) {
  u32 r;
  asm("v_cvt_pk_bf16_f32 %0, %1, %2" : "=v"(r) : "v"(lo), "v"(hi));
  return r;
}

static __device__ __forceinline__ float xhalf_sum(float v) {
#if __has_builtin(__builtin_amdgcn_permlane32_swap)
  u32 a = __float_as_uint(v);
  u32x2 r = __builtin_amdgcn_permlane32_swap(a, a, false, false);
  return __uint_as_float(r[0]) + __uint_as_float(r[1]);
#else
  return v + __shfl_xor(v, 32);
#endif
}

// tau: involution on [0,32): swap bits 0,1 of the 4-group index.
static __device__ __forceinline__ int tau(int p) {
  int g = p >> 2;
  int gk = (g & 4) | ((g & 1) << 1) | ((g >> 1) & 1);
  return (gk << 2) | (p & 3);
}

static __device__ __forceinline__ int fmoff(int row, int col) {
  return (col >> 4) * 512 + (((col >> 3) & 1) * 32 + (row & 31)) * 8 + (col & 7);
}

// ---------------------------------------------------------------------------
// K1: fold weights (FM bf16) + mask all-ones scan. Unchanged.
// ---------------------------------------------------------------------------
__global__ __launch_bounds__(256) void k_prep(const float* __restrict__ qkv_v,
                                              const float* __restrict__ qkv_b,
                                              const float* __restrict__ u_attn,
                                              const float* __restrict__ v_attn,
                                              const float* __restrict__ out_u,
                                              const float* __restrict__ qkv_u,
                                              const float* __restrict__ out_v,
                                              const int* __restrict__ mask,
                                              u16* __restrict__ WQF, u16* __restrict__ WKF,
                                              u16* __restrict__ WVF, float* __restrict__ BQKV,
                                              u16* __restrict__ WOTF, u16* __restrict__ UTF,
                                              u16* __restrict__ OVF, int* __restrict__ flag) {
  __shared__ int mred[4];
  int blk = blockIdx.x;
  int tid = threadIdx.x;
  if (blk < 16) {
    int h = blk;
    int r = tid & 31, g = tid >> 5;
    for (int rp = g; rp < 32; rp += 8) {
      float aq = 0.f, ak = 0.f, av = 0.f;
      for (int d = 0; d < 64; ++d) {
        float u = u_attn[(h * 64 + d) * 32 + r];
        aq += qkv_v[rp * 3072 + h * 64 + d] * u;
        ak += qkv_v[rp * 3072 + 1024 + h * 64 + d] * u;
        av += qkv_v[rp * 3072 + 2048 + h * 64 + d] * u;
      }
      int o = h * 1024 + fmoff(r, rp);
      WQF[o] = f2b(aq);
      WKF[o] = f2b(ak);
      WVF[o] = f2b(av);
    }
    for (int rr = g; rr < 32; rr += 8) {
      float a = 0.f;
      for (int d = 0; d < 64; ++d)
        a += v_attn[(h * 32 + rr) * 64 + d] * out_u[(h * 64 + d) * 32 + r];
      WOTF[fmoff(r, h * 32 + rr)] = f2b(a);
    }
    if (tid < 32) {
      float aq = 0.f, ak = 0.f, av = 0.f;
      for (int d = 0; d < 64; ++d) {
        float u = u_attn[(h * 64 + d) * 32 + r];
        aq += qkv_b[h * 64 + d] * u;
        ak += qkv_b[1024 + h * 64 + d] * u;
        av += qkv_b[2048 + h * 64 + d] * u;
      }
      BQKV[h * 32 + r] = aq;
      BQKV[512 + h * 32 + r] = ak;
      BQKV[1024 + h * 32 + r] = av;
    }
  } else if (blk < 24) {
    int kb = (blk - 16) * 128;
    for (int i = tid; i < 4096; i += 256) {
      int r = i >> 7, kl = i & 127;
      int k = kb + kl;
      UTF[fmoff(r, k)] = f2b(qkv_u[k * 32 + r]);
    }
  } else if (blk < 32) {
    int db = (blk - 24) * 128;
    for (int i = tid; i < 4096; i += 256) {
      int dl = i >> 5, r = i & 31;
      int d = db + dl;
      OVF[(d >> 5) * 1024 + fmoff(d, r)] = f2b(out_v[r * 1024 + d]);
    }
  } else {
    int mall = 1;
    for (int i = tid; i < 8192; i += 256) mall &= (mask[i] != 0) ? 1 : 0;
    int wa = __all(mall) ? 1 : 0;
    if ((tid & 63) == 0) mred[tid >> 6] = wa;
    __syncthreads();
    if (tid == 0) flag[0] = mred[0] & mred[1] & mred[2] & mred[3];
  }
}

// ---------------------------------------------------------------------------
// K2 (fused proj+lowproj): unchanged from r12.
// ---------------------------------------------------------------------------
__global__ __launch_bounds__(512) void k_projlow(const float* __restrict__ x,
                                                 const u16* __restrict__ UTF,
                                                 const u16* __restrict__ WQF,
                                                 const u16* __restrict__ WKF,
                                                 const u16* __restrict__ WVF,
                                                 const float* __restrict__ BQKV,
                                                 u16* __restrict__ QLF, u16* __restrict__ KF,
                                                 u16* __restrict__ VF) {
  __shared__ float xl[2][32][129];
  __shared__ float red[8][32][33];
  int tid = threadIdx.x;
  int w = tid >> 6, l = tid & 63, lo = l & 31, hi = l >> 5;
  int stile = blockIdx.x;
  int b = stile >> 6, qt = stile & 63;
  int m0 = stile * 32;

  {
    int srow = tid >> 4, scol = (tid & 15) * 8;
    const float* xp = x + (size_t)(m0 + srow) * 1024 + scol;
    float4 r0 = *(const float4*)(xp);
    float4 r1 = *(const float4*)(xp + 4);
    xp += 128;
    f32x16 acc = {};
    for (int ch = 0; ch < 8; ++ch) {
      int buf = ch & 1;
      float* dst = &xl[buf][srow][scol];
      dst[0] = r0.x; dst[1] = r0.y; dst[2] = r0.z; dst[3] = r0.w;
      dst[4] = r1.x; dst[5] = r1.y; dst[6] = r1.z; dst[7] = r1.w;
      if (ch < 7) {
        r0 = *(const float4*)(xp);
        r1 = *(const float4*)(xp + 4);
        xp += 128;
      }
      __syncthreads();
      const float* src = &xl[buf][lo][w * 16 + hi * 8];
      union { bf16x8 v; u32 u[4]; } af;
      af.u[0] = cvtpk(src[0], src[1]);
      af.u[1] = cvtpk(src[2], src[3]);
      af.u[2] = cvtpk(src[4], src[5]);
      af.u[3] = cvtpk(src[6], src[7]);
      bf16x8 bf = *(const bf16x8*)(UTF + (ch * 8 + w) * 512 + l * 8);
      acc = MFMA(af.v, bf, acc, 0, 0, 0);
    }
#pragma unroll
    for (int i = 0; i < 16; ++i)
      red[w][(i & 3) + 8 * (i >> 2) + 4 * hi][lo] = acc[i];
  }
  __syncthreads();
  u16* tl = (u16*)&xl[0][0][0];
  {
    int m = tid >> 4, c = (tid & 15) * 2;
    float v0 = 0.f, v1 = 0.f;
#pragma unroll
    for (int ww = 0; ww < 8; ++ww) {
      v0 += red[ww][m][c + 0];
      v1 += red[ww][m][c + 1];
    }
    *(u32*)(tl + fmoff(m, c)) = cvtpk(v0, v1);
  }
  __syncthreads();

  bf16x8 tb0 = *(const bf16x8*)(tl + l * 8);
  bf16x8 tb1 = *(const bf16x8*)(tl + 512 + l * 8);
  for (int hh = 0; hh < 2; ++hh) {
    int h = w * 2 + hh;
    int bh = b * 16 + h;
    const u16* wq = WQF + h * 1024 + l * 8;
    const u16* wk = WKF + h * 1024 + l * 8;
    const u16* wv = WVF + h * 1024 + l * 8;
    bf16x8 aq0 = *(const bf16x8*)(wq), aq1 = *(const bf16x8*)(wq + 512);
    bf16x8 ak0 = *(const bf16x8*)(wk), ak1 = *(const bf16x8*)(wk + 512);
    bf16x8 av0 = *(const bf16x8*)(wv), av1 = *(const bf16x8*)(wv + 512);

    f32x16 cq = {}, ck = {}, cv = {};
    cq = MFMA(aq0, tb0, cq, 0, 0, 0);
    cq = MFMA(aq1, tb1, cq, 0, 0, 0);
    ck = MFMA(ak0, tb0, ck, 0, 0, 0);
    ck = MFMA(ak1, tb1, ck, 0, 0, 0);
    cv = MFMA(av0, tb0, cv, 0, 0, 0);
    cv = MFMA(av1, tb1, cv, 0, 0, 0);

    size_t base = (size_t)bh * 65536 + (size_t)qt * 1024;
    int slp = tau(lo);
#pragma unroll
    for (int g2 = 0; g2 < 4; ++g2) {
      float4 bq4 = *(const float4*)(BQKV + h * 32 + g2 * 8 + 4 * hi);
      float4 bk4 = *(const float4*)(BQKV + 512 + h * 32 + g2 * 8 + 4 * hi);
      float4 bv4 = *(const float4*)(BQKV + 1024 + h * 32 + g2 * 8 + 4 * hi);
      float q0 = (cq[4 * g2 + 0] + bq4.x) * QSCALE;
      float q1 = (cq[4 * g2 + 1] + bq4.y) * QSCALE;
      float q2 = (cq[4 * g2 + 2] + bq4.z) * QSCALE;
      float q3 = (cq[4 * g2 + 3] + bq4.w) * QSCALE;
      uint2 qo; qo.x = cvtpk(q0, q1); qo.y = cvtpk(q2, q3);
      *(uint2*)(QLF + base + (g2 >> 1) * 512 + ((g2 & 1) * 32 + lo) * 8 + 4 * hi) = qo;
      uint2 ko;
      ko.x = cvtpk(ck[4 * g2 + 0] + bk4.x, ck[4 * g2 + 1] + bk4.y);
      ko.y = cvtpk(ck[4 * g2 + 2] + bk4.z, ck[4 * g2 + 3] + bk4.w);
      *(uint2*)(KF + base + (g2 >> 1) * 512 + (g2 & 1) * 256 + lo * 8 + 4 * hi) = ko;
      int rbase = g2 * 8 + 4 * hi;
      red[w][rbase + 0][slp] = cv[4 * g2 + 0] + bv4.x;
      red[w][rbase + 1][slp] = cv[4 * g2 + 1] + bv4.y;
      red[w][rbase + 2][slp] = cv[4 * g2 + 2] + bv4.z;
      red[w][rbase + 3][slp] = cv[4 * g2 + 3] + bv4.w;
    }
    for (int u = l; u < 128; u += 64) {
      int r = u >> 2, su = (u & 3) * 8;
      const float* src = &red[w][r][su];
      uint4 o;
      o.x = cvtpk(src[0], src[1]);
      o.y = cvtpk(src[2], src[3]);
      o.z = cvtpk(src[4], src[5]);
      o.w = cvtpk(src[6], src[7]);
      *(uint4*)(VF + base + (su >> 4) * 512 + ((su >> 3) & 1) * 256 + r * 8) = o;
    }
  }
}

// ---------------------------------------------------------------------------
// K4: flash attention. r13 change: DUAL-STREAM hot loop -- the wave's 32
// key-tiles split into two independent 16-tile streams (additive partials),
// interleaved per iteration so stream B's MFMAs/loads cover stream A's
// quarter-rate exp2 latency (r12: VALUBusy 61%, ~23us stall slack).
// Trades occupancy (VGPR up from 64) for 2x per-wave ILP.
// ---------------------------------------------------------------------------
__global__ __launch_bounds__(256) void k_attn(const u16* __restrict__ QLF,
                                              const u16* __restrict__ KF,
                                              const u16* __restrict__ VF,
                                              const int* __restrict__ mask,
                                              const int* __restrict__ flag,
                                              u16* __restrict__ CTX2) {
  __shared__ float pacc[2][64][17];
  __shared__ float pl[2][64];
  __shared__ u32 cls[64][17];
  int tid = threadIdx.x;
  int wave = tid >> 6, l = tid & 63, lo = l & 31, hi = l >> 5;
  int blk = blockIdx.x;
  int xcd = blk & 7, slot = blk >> 3;
  int bh = xcd * 8 + (slot >> 5);
  int qpair = slot & 31;
  int qi = wave & 1;
  int khalf = wave >> 1;
  int qt = qpair * 2 + qi;
  int b = bh >> 4, h = bh & 15;

  const u16* qp = QLF + (size_t)bh * 65536 + (size_t)qt * 1024 + l * 8;
  bf16x8 qb0 = *(const bf16x8*)(qp);
  bf16x8 qb1 = *(const bf16x8*)(qp + 512);

  size_t fbase = (size_t)bh * 65536 + (size_t)khalf * 32768 + l * 8;
  const u16* kp = KF + fbase;
  const u16* vp = VF + fbase;

  f32x16 acc = {};
  float l_run = 0.f;

  if (flag[0]) {
    // hot path: two independent 16-tile streams (A: tiles 0..15, B: 16..31)
    const u16* kpA = kp;
    const u16* vpA = vp;
    const u16* kpB = kp + 16 * 1024;
    const u16* vpB = vp + 16 * 1024;
    f32x16 acc2 = {};
    float l_run2 = 0.f;
#pragma unroll 1
    for (int kt = 0; kt < 16; ++kt) {
      bf16x8 ka0A = *(const bf16x8*)(kpA);
      bf16x8 ka1A = *(const bf16x8*)(kpA + 512);
      kpA += 1024;
      bf16x8 ka0B = *(const bf16x8*)(kpB);
      bf16x8 ka1B = *(const bf16x8*)(kpB + 512);
      kpB += 1024;
      f32x16 scA = {};
      scA = MFMA(ka0A, qb0, scA, 0, 0, 0);
      scA = MFMA(ka1A, qb1, scA, 0, 0, 0);
      f32x16 scB = {};
      scB = MFMA(ka0B, qb0, scB, 0, 0, 0);
      scB = MFMA(ka1B, qb1, scB, 0, 0, 0);
      bf16x8 va0A = *(const bf16x8*)(vpA);
      bf16x8 va1A = *(const bf16x8*)(vpA + 512);
      vpA += 1024;
      bf16x8 va0B = *(const bf16x8*)(vpB);
      bf16x8 va1B = *(const bf16x8*)(vpB + 512);
      vpB += 1024;
      // stream A softmax + PV
      {
        union { bf16x8 v; u32 u[4]; } fa;
        float a0 = __builtin_amdgcn_exp2f(scA[0]);
        float a1 = __builtin_amdgcn_exp2f(scA[1]);
        float a2 = __builtin_amdgcn_exp2f(scA[2]);
        float a3 = __builtin_amdgcn_exp2f(scA[3]);
        fa.u[0] = cvtpk(a0, a1);
        fa.u[1] = cvtpk(a2, a3);
        float t0 = (a0 + a1) + (a2 + a3);
        a0 = __builtin_amdgcn_exp2f(scA[4]);
        a1 = __builtin_amdgcn_exp2f(scA[5]);
        a2 = __builtin_amdgcn_exp2f(scA[6]);
        a3 = __builtin_amdgcn_exp2f(scA[7]);
        fa.u[2] = cvtpk(a0, a1);
        fa.u[3] = cvtpk(a2, a3);
        float t1 = (a0 + a1) + (a2 + a3);
        acc = MFMA(va0A, fa.v, acc, 0, 0, 0);
        union { bf16x8 v; u32 u[4]; } fc;
        a0 = __builtin_amdgcn_exp2f(scA[8]);
        a1 = __builtin_amdgcn_exp2f(scA[9]);
        a2 = __builtin_amdgcn_exp2f(scA[10]);
        a3 = __builtin_amdgcn_exp2f(scA[11]);
        fc.u[0] = cvtpk(a0, a1);
        fc.u[1] = cvtpk(a2, a3);
        float t2 = (a0 + a1) + (a2 + a3);
        a0 = __builtin_amdgcn_exp2f(scA[12]);
        a1 = __builtin_amdgcn_exp2f(scA[13]);
        a2 = __builtin_amdgcn_exp2f(scA[14]);
        a3 = __builtin_amdgcn_exp2f(scA[15]);
        fc.u[2] = cvtpk(a0, a1);
        fc.u[3] = cvtpk(a2, a3);
        float t3 = (a0 + a1) + (a2 + a3);
        acc = MFMA(va1A, fc.v, acc, 0, 0, 0);
        l_run += (t0 + t1) + (t2 + t3);
      }
      // stream B softmax + PV
      {
        union { bf16x8 v; u32 u[4]; } fa;
        float a0 = __builtin_amdgcn_exp2f(scB[0]);
        float a1 = __builtin_amdgcn_exp2f(scB[1]);
        float a2 = __builtin_amdgcn_exp2f(scB[2]);
        float a3 = __builtin_amdgcn_exp2f(scB[3]);
        fa.u[0] = cvtpk(a0, a1);
        fa.u[1] = cvtpk(a2, a3);
        float t0 = (a0 + a1) + (a2 + a3);
        a0 = __builtin_amdgcn_exp2f(scB[4]);
        a1 = __builtin_amdgcn_exp2f(scB[5]);
        a2 = __builtin_amdgcn_exp2f(scB[6]);
        a3 = __builtin_amdgcn_exp2f(scB[7]);
        fa.u[2] = cvtpk(a0, a1);
        fa.u[3] = cvtpk(a2, a3);
        float t1 = (a0 + a1) + (a2 + a3);
        acc2 = MFMA(va0B, fa.v, acc2, 0, 0, 0);
        union { bf16x8 v; u32 u[4]; } fc;
        a0 = __builtin_amdgcn_exp2f(scB[8]);
        a1 = __builtin_amdgcn_exp2f(scB[9]);
        a2 = __builtin_amdgcn_exp2f(scB[10]);
        a3 = __builtin_amdgcn_exp2f(scB[11]);
        fc.u[0] = cvtpk(a0, a1);
        fc.u[1] = cvtpk(a2, a3);
        float t2 = (a0 + a1) + (a2 + a3);
        a0 = __builtin_amdgcn_exp2f(scB[12]);
        a1 = __builtin_amdgcn_exp2f(scB[13]);
        a2 = __builtin_amdgcn_exp2f(scB[14]);
        a3 = __builtin_amdgcn_exp2f(scB[15]);
        fc.u[2] = cvtpk(a0, a1);
        fc.u[3] = cvtpk(a2, a3);
        float t3 = (a0 + a1) + (a2 + a3);
        acc2 = MFMA(va1B, fc.v, acc2, 0, 0, 0);
        l_run2 += (t0 + t1) + (t2 + t3);
      }
    }
#pragma unroll
    for (int i = 0; i < 16; ++i) acc[i] += acc2[i];
    l_run += l_run2;
  } else {
    // cold path: general masked loop (single stream, unchanged)
    const int* mp = mask + b * 2048 + khalf * 1024 + lo;
#pragma unroll 1
    for (int kt = 0; kt < 32; ++kt) {
      unsigned long long bm = __ballot(mp[0] != 0);
      mp += 32;
      bf16x8 ka0 = *(const bf16x8*)(kp);
      bf16x8 ka1 = *(const bf16x8*)(kp + 512);
      kp += 1024;
      f32x16 sc = {};
      sc = MFMA(ka0, qb0, sc, 0, 0, 0);
      sc = MFMA(ka1, qb1, sc, 0, 0, 0);
      u32 km = (u32)bm;
#pragma unroll
      for (int i = 0; i < 16; ++i) {
        int key = (i & 3) + 8 * (i >> 2) + 4 * hi;
        if (!((km >> key) & 1)) sc[i] = -3.0e38f;
      }
      bf16x8 va0 = *(const bf16x8*)(vp);
      bf16x8 va1 = *(const bf16x8*)(vp + 512);
      vp += 1024;
      union { bf16x8 v; u32 u[4]; } fa;
      float a0 = __builtin_amdgcn_exp2f(sc[0]);
      float a1 = __builtin_amdgcn_exp2f(sc[1]);
      float a2 = __builtin_amdgcn_exp2f(sc[2]);
      float a3 = __builtin_amdgcn_exp2f(sc[3]);
      fa.u[0] = cvtpk(a0, a1);
      fa.u[1] = cvtpk(a2, a3);
      float t0 = (a0 + a1) + (a2 + a3);
      a0 = __builtin_amdgcn_exp2f(sc[4]);
      a1 = __builtin_amdgcn_exp2f(sc[5]);
      a2 = __builtin_amdgcn_exp2f(sc[6]);
      a3 = __builtin_amdgcn_exp2f(sc[7]);
      fa.u[2] = cvtpk(a0, a1);
      fa.u[3] = cvtpk(a2, a3);
      float t1 = (a0 + a1) + (a2 + a3);
      acc = MFMA(va0, fa.v, acc, 0, 0, 0);
      union { bf16x8 v; u32 u[4]; } fc;
      a0 = __builtin_amdgcn_exp2f(sc[8]);
      a1 = __builtin_amdgcn_exp2f(sc[9]);
      a2 = __builtin_amdgcn_exp2f(sc[10]);
      a3 = __builtin_amdgcn_exp2f(sc[11]);
      fc.u[0] = cvtpk(a0, a1);
      fc.u[1] = cvtpk(a2, a3);
      float t2 = (a0 + a1) + (a2 + a3);
      a0 = __builtin_amdgcn_exp2f(sc[12]);
      a1 = __builtin_amdgcn_exp2f(sc[13]);
      a2 = __builtin_amdgcn_exp2f(sc[14]);
      a3 = __builtin_amdgcn_exp2f(sc[15]);
      fc.u[2] = cvtpk(a0, a1);
      fc.u[3] = cvtpk(a2, a3);
      float t3 = (a0 + a1) + (a2 + a3);
      acc = MFMA(va1, fc.v, acc, 0, 0, 0);
      l_run += (t0 + t1) + (t2 + t3);
    }
  }

  if (khalf) {
#pragma unroll
    for (int i = 0; i < 16; ++i) pacc[qi][l][i] = acc[i];
    pl[qi][l] = l_run;
  }
  __syncthreads();
  if (!khalf) {
#pragma unroll
    for (int i = 0; i < 16; ++i) acc[i] += pacc[qi][l][i];
    l_run += pl[qi][l];
    l_run = xhalf_sum(l_run);
    float inv = 1.0f / l_run;
    int qloc = qi * 32 + lo;
#pragma unroll
    for (int g2 = 0; g2 < 4; ++g2) {
      cls[qloc][g2 * 4 + 2 * hi] = cvtpk(acc[4 * g2 + 0] * inv, acc[4 * g2 + 1] * inv);
      cls[qloc][g2 * 4 + 2 * hi + 1] = cvtpk(acc[4 * g2 + 2] * inv, acc[4 * g2 + 3] * inv);
    }
  }
  __syncthreads();
  int st2 = tid >> 7, kcl = (tid >> 6) & 1, lw = tid & 63;
  const u32* src = &cls[st2 * 32 + (lw & 31)][kcl * 8 + (lw >> 5) * 4];
  uint4 v0;
  v0.x = src[0]; v0.y = src[1]; v0.z = src[2]; v0.w = src[3];
  *(uint4*)(CTX2 + (size_t)(b * 64 + qpair * 2 + st2) * 16384 +
            (2 * h + kcl) * 512 + lw * 8) = v0;
}

// ---------------------------------------------------------------------------
// K5 (fused epi1+epi2): unchanged from r12.
// ---------------------------------------------------------------------------
__global__ __launch_bounds__(512) void k_epi(const u16* __restrict__ CTX2,
                                             const u16* __restrict__ WOTF,
                                             const u16* __restrict__ OVF,
                                             const float* __restrict__ out_b,
                                             float* __restrict__ out) {
  __shared__ float red[8][32][33];
  __shared__ u32 yl[32][17];
  int tid = threadIdx.x;
  int w = tid >> 6, l = tid & 63, lo = l & 31, hi = l >> 5;
  int stile = blockIdx.x;
  int s0 = stile * 32;
  {
    const u16* cp = CTX2 + (size_t)stile * 16384 + (4 * w) * 512 + l * 8;
    const u16* wp = WOTF + (4 * w) * 512 + l * 8;
    f32x16 acc = {};
    for (int st = 0; st < 4; ++st) {
      bf16x8 a = *(const bf16x8*)(cp);
      bf16x8 bb = *(const bf16x8*)(wp);
      cp += 512;
      wp += 512;
      acc = MFMA(a, bb, acc, 0, 0, 0);
    }
#pragma unroll
    for (int i = 0; i < 16; ++i)
      red[w][(i & 3) + 8 * (i >> 2) + 4 * hi][lo] = acc[i];
  }
  __syncthreads();
  {
    int m = tid >> 4, c = (tid & 15) * 2;
    float v0 = 0.f, v1 = 0.f;
#pragma unroll
    for (int ww = 0; ww < 8; ++ww) {
      v0 += red[ww][m][c + 0];
      v1 += red[ww][m][c + 1];
    }
    yl[m][c >> 1] = cvtpk(v0, v1);
  }
  __syncthreads();
  float (*ol)[263] = (float(*)[263])&red[0][0][0];
  union { bf16x8 v; u32 u[4]; } ub0, ub1;
#pragma unroll
  for (int j = 0; j < 4; ++j) {
    ub0.u[j] = yl[lo][hi * 4 + j];
    ub1.u[j] = yl[lo][8 + hi * 4 + j];
  }
  for (int p = 0; p < 4; ++p) {
    int dtile = p * 8 + w;
    const u16* ap = OVF + (size_t)dtile * 1024 + l * 8;
    bf16x8 a0 = *(const bf16x8*)(ap), a1 = *(const bf16x8*)(ap + 512);
    f32x16 acc = {};
    acc = MFMA(a0, ub0.v, acc, 0, 0, 0);
    acc = MFMA(a1, ub1.v, acc, 0, 0, 0);
#pragma unroll
    for (int i = 0; i < 16; ++i)
      ol[lo][w * 32 + (i & 3) + 8 * (i >> 2) + 4 * hi] = acc[i];
    __syncthreads();
    for (int u = tid; u < 2048; u += 512) {
      int s = u >> 6, c4 = (u & 63) * 4;
      float4 ob = *(const float4*)(out_b + p * 256 + c4);
      float4 o;
      o.x = ol[s][c4 + 0] + ob.x;
      o.y = ol[s][c4 + 1] + ob.y;
      o.z = ol[s][c4 + 2] + ob.z;
      o.w = ol[s][c4 + 3] + ob.w;
      *(float4*)(out + (size_t)(s0 + s) * 1024 + p * 256 + c4) = o;
    }
    __syncthreads();
  }
}

extern "C" void kernel_launch(void* const* d_in, const int* in_sizes, int n_in,
                              void* d_out, int out_size, void* d_ws, size_t ws_size,
                              hipStream_t stream) {
  const float* x = (const float*)d_in[0];
  const int* mask = (const int*)d_in[1];
  const float* qkv_u = (const float*)d_in[2];
  const float* qkv_v = (const float*)d_in[3];
  const float* qkv_b = (const float*)d_in[4];
  const float* u_attn = (const float*)d_in[5];
  const float* v_attn = (const float*)d_in[6];
  const float* out_u = (const float*)d_in[7];
  const float* out_v = (const float*)d_in[8];
  const float* out_b = (const float*)d_in[9];
  float* out = (float*)d_out;

  char* w = (char*)d_ws;
  u16* WQF = (u16*)(w + 0);                // 32 KB
  u16* WKF = (u16*)(w + (32 << 10));       // 32 KB
  u16* WVF = (u16*)(w + (64 << 10));       // 32 KB
  float* BQ = (float*)(w + (96 << 10));    // 6 KB
  int* FLAG = (int*)(w + (102 << 10));     // 4 B
  u16* WOTF = (u16*)(w + (104 << 10));     // 32 KB
  u16* UTF = (u16*)(w + (136 << 10));      // 64 KB
  u16* OVF = (u16*)(w + (200 << 10));      // 64 KB
  u16* QLF = (u16*)(w + (2 << 20));        // 8 MB bf16 FM [bh][qt][kc]
  u16* KF = (u16*)(w + (10 << 20));        // 8 MB bf16 FM [bh][tile]
  u16* VF = (u16*)(w + (18 << 20));        // 8 MB bf16 FM [bh][tile] (tau)
  u16* CTX2 = (u16*)(w + (26 << 20));      // 8 MB bf16 FM [256 stiles][32 kc]

  k_prep<<<33, 256, 0, stream>>>(qkv_v, qkv_b, u_attn, v_attn, out_u, qkv_u, out_v,
                                 mask, WQF, WKF, WVF, BQ, WOTF, UTF, OVF, FLAG);
  k_projlow<<<256, 512, 0, stream>>>(x, UTF, WQF, WKF, WVF, BQ, QLF, KF, VF);
  k_attn<<<2048, 256, 0, stream>>>(QLF, KF, VF, mask, FLAG, CTX2);
  k_epi<<<256, 512, 0, stream>>>(CTX2, WOTF, OVF, out_b, out);
}

// Round 14
// 111.939 us; speedup vs baseline: 1.0641x; 1.0641x over previous
//
#include <hip/hip_runtime.h>
#include <hip/hip_bf16.h>

typedef unsigned int u32;
typedef unsigned short u16;
typedef __attribute__((ext_vector_type(8))) __bf16 bf16x8;
typedef __attribute__((ext_vector_type(16))) float f32x16;
typedef __attribute__((ext_vector_type(2))) unsigned int u32x2;

// log2(e)/sqrt(32): folds exp->exp2 and 1/sqrt(rank) into Q.
#define QSCALE 0.25505418f
#define MFMA __builtin_amdgcn_mfma_f32_32x32x16_bf16

// Fragment-major (FM) layout for a 32-row x 16-col bf16 MFMA operand tile:
// lane l holds row (l&31), cols (l>>5)*8 + 0..7 -> flat slot = lane*8 + e.
// A 32x32 operand = 2 kchunks (512 u16). All global operands stored FM so
// hot loops load "base + l*8": coalesced 1KB/wave bursts (r7/r10 ladder).
// r13 lesson: dual-stream ILP (72 VGPR) lost to occupancy; r11 config is
// the measured optimum -- this file is the r11 build.

static __device__ __forceinline__ u16 f2b(float f) {
  __hip_bfloat16 h = __float2bfloat16(f);
  return *reinterpret_cast<u16*>(&h);
}
static __device__ __forceinline__ u32 cvtpk(float lo, float hi) {
  u32 r;
  asm("v_cvt_pk_bf16_f32 %0, %1, %2" : "=v"(r) : "v"(lo), "v"(hi));
  return r;
}

static __device__ __forceinline__ float xhalf_sum(float v) {
#if __has_builtin(__builtin_amdgcn_permlane32_swap)
  u32 a = __float_as_uint(v);
  u32x2 r = __builtin_amdgcn_permlane32_swap(a, a, false, false);
  return __uint_as_float(r[0]) + __uint_as_float(r[1]);
#else
  return v + __shfl_xor(v, 32);
#endif
}

// tau: involution on [0,32): swap bits 0,1 of the 4-group index.
static __device__ __forceinline__ int tau(int p) {
  int g = p >> 2;
  int gk = (g & 4) | ((g & 1) << 1) | ((g >> 1) & 1);
  return (gk << 2) | (p & 3);
}

static __device__ __forceinline__ int fmoff(int row, int col) {
  return (col >> 4) * 512 + (((col >> 3) & 1) * 32 + (row & 31)) * 8 + (col & 7);
}

// ---------------------------------------------------------------------------
// K1: fold weights (FM bf16) + mask all-ones scan.
// ---------------------------------------------------------------------------
__global__ __launch_bounds__(256) void k_prep(const float* __restrict__ qkv_v,
                                              const float* __restrict__ qkv_b,
                                              const float* __restrict__ u_attn,
                                              const float* __restrict__ v_attn,
                                              const float* __restrict__ out_u,
                                              const float* __restrict__ qkv_u,
                                              const float* __restrict__ out_v,
                                              const int* __restrict__ mask,
                                              u16* __restrict__ WQF, u16* __restrict__ WKF,
                                              u16* __restrict__ WVF, float* __restrict__ BQKV,
                                              u16* __restrict__ WOTF, u16* __restrict__ UTF,
                                              u16* __restrict__ OVF, int* __restrict__ flag) {
  __shared__ int mred[4];
  int blk = blockIdx.x;
  int tid = threadIdx.x;
  if (blk < 16) {
    int h = blk;
    int r = tid & 31, g = tid >> 5;
    for (int rp = g; rp < 32; rp += 8) {
      float aq = 0.f, ak = 0.f, av = 0.f;
      for (int d = 0; d < 64; ++d) {
        float u = u_attn[(h * 64 + d) * 32 + r];
        aq += qkv_v[rp * 3072 + h * 64 + d] * u;
        ak += qkv_v[rp * 3072 + 1024 + h * 64 + d] * u;
        av += qkv_v[rp * 3072 + 2048 + h * 64 + d] * u;
      }
      int o = h * 1024 + fmoff(r, rp);
      WQF[o] = f2b(aq);
      WKF[o] = f2b(ak);
      WVF[o] = f2b(av);
    }
    for (int rr = g; rr < 32; rr += 8) {
      float a = 0.f;
      for (int d = 0; d < 64; ++d)
        a += v_attn[(h * 32 + rr) * 64 + d] * out_u[(h * 64 + d) * 32 + r];
      WOTF[fmoff(r, h * 32 + rr)] = f2b(a);
    }
    if (tid < 32) {
      float aq = 0.f, ak = 0.f, av = 0.f;
      for (int d = 0; d < 64; ++d) {
        float u = u_attn[(h * 64 + d) * 32 + r];
        aq += qkv_b[h * 64 + d] * u;
        ak += qkv_b[1024 + h * 64 + d] * u;
        av += qkv_b[2048 + h * 64 + d] * u;
      }
      BQKV[h * 32 + r] = aq;
      BQKV[512 + h * 32 + r] = ak;
      BQKV[1024 + h * 32 + r] = av;
    }
  } else if (blk < 24) {
    int kb = (blk - 16) * 128;
    for (int i = tid; i < 4096; i += 256) {
      int r = i >> 7, kl = i & 127;
      int k = kb + kl;
      UTF[fmoff(r, k)] = f2b(qkv_u[k * 32 + r]);
    }
  } else if (blk < 32) {
    int db = (blk - 24) * 128;
    for (int i = tid; i < 4096; i += 256) {
      int dl = i >> 5, r = i & 31;
      int d = db + dl;
      OVF[(d >> 5) * 1024 + fmoff(d, r)] = f2b(out_v[r * 1024 + d]);
    }
  } else {
    int mall = 1;
    for (int i = tid; i < 8192; i += 256) mall &= (mask[i] != 0) ? 1 : 0;
    int wa = __all(mall) ? 1 : 0;
    if ((tid & 63) == 0) mred[tid >> 6] = wa;
    __syncthreads();
    if (tid == 0) flag[0] = mred[0] & mred[1] & mred[2] & mred[3];
  }
}

// ---------------------------------------------------------------------------
// K2: T = x @ qkv_u -> TF fragment-major. 512 thr. x staged through
// double-buffered LDS with next-chunk loads issued one iteration ahead.
// ---------------------------------------------------------------------------
__global__ __launch_bounds__(512) void k_proj(const float* __restrict__ x,
                                              const u16* __restrict__ UTF,
                                              u16* __restrict__ TF) {
  __shared__ float xl[2][32][129];
  __shared__ float red[8][32][33];
  int tid = threadIdx.x;
  int w = tid >> 6, l = tid & 63, lo = l & 31, hi = l >> 5;
  int m0 = blockIdx.x * 32;
  int srow = tid >> 4, scol = (tid & 15) * 8;
  const float* xp = x + (size_t)(m0 + srow) * 1024 + scol;
  float4 r0 = *(const float4*)(xp);
  float4 r1 = *(const float4*)(xp + 4);
  xp += 128;
  f32x16 acc = {};
  for (int ch = 0; ch < 8; ++ch) {
    int buf = ch & 1;
    float* dst = &xl[buf][srow][scol];
    dst[0] = r0.x; dst[1] = r0.y; dst[2] = r0.z; dst[3] = r0.w;
    dst[4] = r1.x; dst[5] = r1.y; dst[6] = r1.z; dst[7] = r1.w;
    if (ch < 7) {
      r0 = *(const float4*)(xp);
      r1 = *(const float4*)(xp + 4);
      xp += 128;
    }
    __syncthreads();
    const float* src = &xl[buf][lo][w * 16 + hi * 8];
    union { bf16x8 v; u32 u[4]; } af;
    af.u[0] = cvtpk(src[0], src[1]);
    af.u[1] = cvtpk(src[2], src[3]);
    af.u[2] = cvtpk(src[4], src[5]);
    af.u[3] = cvtpk(src[6], src[7]);
    bf16x8 bf = *(const bf16x8*)(UTF + (ch * 8 + w) * 512 + l * 8);
    acc = MFMA(af.v, bf, acc, 0, 0, 0);
  }
#pragma unroll
  for (int i = 0; i < 16; ++i)
    red[w][(i & 3) + 8 * (i >> 2) + 4 * hi][lo] = acc[i];
  __syncthreads();
  int m = tid >> 4, c = (tid & 15) * 2;
  float v0 = 0.f, v1 = 0.f;
#pragma unroll
  for (int ww = 0; ww < 8; ++ww) {
    v0 += red[ww][m][c + 0];
    v1 += red[ww][m][c + 1];
  }
  *(u32*)(TF + (size_t)blockIdx.x * 1024 + fmoff(m, c)) = cvtpk(v0, v1);
}

// ---------------------------------------------------------------------------
// K3: per-head low-rank Q/K/V via MFMA. All operand reads fragment-major.
// QLF [bh][64 qtiles][2 kchunks] FM; KF/VF [bh][tile][1024] FM (VF tau).
// ---------------------------------------------------------------------------
__global__ __launch_bounds__(256) void k_lowproj(const u16* __restrict__ TF,
                                                 const u16* __restrict__ WQF,
                                                 const u16* __restrict__ WKF,
                                                 const u16* __restrict__ WVF,
                                                 const float* __restrict__ BQKV,
                                                 u16* __restrict__ QLF, u16* __restrict__ KF,
                                                 u16* __restrict__ VF) {
  __shared__ float vtf[32][132];
  int tid = threadIdx.x;
  int w = tid >> 6, l = tid & 63, lo = l & 31, hi = l >> 5;
  int blk = blockIdx.x;  // 64 bh * 16 sblocks
  int bh = blk >> 4, sb = (blk & 15) * 128;
  int b = bh >> 4, h = bh & 15;
  int qt = (sb >> 5) + w;

  const u16* wq = WQF + h * 1024 + l * 8;
  const u16* wk = WKF + h * 1024 + l * 8;
  const u16* wv = WVF + h * 1024 + l * 8;
  bf16x8 aq0 = *(const bf16x8*)(wq), aq1 = *(const bf16x8*)(wq + 512);
  bf16x8 ak0 = *(const bf16x8*)(wk), ak1 = *(const bf16x8*)(wk + 512);
  bf16x8 av0 = *(const bf16x8*)(wv), av1 = *(const bf16x8*)(wv + 512);

  const u16* tp = TF + (size_t)(b * 64 + qt) * 1024 + l * 8;
  bf16x8 tb0 = *(const bf16x8*)(tp), tb1 = *(const bf16x8*)(tp + 512);

  f32x16 cq = {}, ck = {}, cv = {};
  cq = MFMA(aq0, tb0, cq, 0, 0, 0);
  cq = MFMA(aq1, tb1, cq, 0, 0, 0);
  ck = MFMA(ak0, tb0, ck, 0, 0, 0);
  ck = MFMA(ak1, tb1, ck, 0, 0, 0);
  cv = MFMA(av0, tb0, cv, 0, 0, 0);
  cv = MFMA(av1, tb1, cv, 0, 0, 0);

  size_t qbase = (size_t)bh * 65536 + (size_t)qt * 1024;
  size_t tbase = (size_t)bh * 65536 + (size_t)qt * 1024;
  int slp = w * 32 + tau(lo);
#pragma unroll
  for (int g2 = 0; g2 < 4; ++g2) {
    float4 bq4 = *(const float4*)(BQKV + h * 32 + g2 * 8 + 4 * hi);
    float4 bk4 = *(const float4*)(BQKV + 512 + h * 32 + g2 * 8 + 4 * hi);
    float4 bv4 = *(const float4*)(BQKV + 1024 + h * 32 + g2 * 8 + 4 * hi);
    float q0 = (cq[4 * g2 + 0] + bq4.x) * QSCALE;
    float q1 = (cq[4 * g2 + 1] + bq4.y) * QSCALE;
    float q2 = (cq[4 * g2 + 2] + bq4.z) * QSCALE;
    float q3 = (cq[4 * g2 + 3] + bq4.w) * QSCALE;
    uint2 qo; qo.x = cvtpk(q0, q1); qo.y = cvtpk(q2, q3);
    *(uint2*)(QLF + qbase + (g2 >> 1) * 512 + ((g2 & 1) * 32 + lo) * 8 + 4 * hi) = qo;
    uint2 ko;
    ko.x = cvtpk(ck[4 * g2 + 0] + bk4.x, ck[4 * g2 + 1] + bk4.y);
    ko.y = cvtpk(ck[4 * g2 + 2] + bk4.z, ck[4 * g2 + 3] + bk4.w);
    *(uint2*)(KF + tbase + (g2 >> 1) * 512 + (g2 & 1) * 256 + lo * 8 + 4 * hi) = ko;
    int rbase = g2 * 8 + 4 * hi;
    vtf[rbase + 0][slp] = cv[4 * g2 + 0] + bv4.x;
    vtf[rbase + 1][slp] = cv[4 * g2 + 1] + bv4.y;
    vtf[rbase + 2][slp] = cv[4 * g2 + 2] + bv4.z;
    vtf[rbase + 3][slp] = cv[4 * g2 + 3] + bv4.w;
  }
  __syncthreads();
  for (int u = tid; u < 512; u += 256) {
    int r = u >> 4, su = (u & 15) * 8;
    const float* src = &vtf[r][su];
    uint4 o;
    o.x = cvtpk(src[0], src[1]);
    o.y = cvtpk(src[2], src[3]);
    o.z = cvtpk(src[4], src[5]);
    o.w = cvtpk(src[6], src[7]);
    int c = su & 31, tloc = su >> 5;
    *(uint4*)(VF + (size_t)bh * 65536 + (size_t)((sb >> 5) + tloc) * 1024 +
              (c >> 4) * 512 + ((c >> 3) & 1) * 256 + r * 8) = o;
  }
}

// ---------------------------------------------------------------------------
// K4: flash attention (swapped-operand 32x32x16 MFMA). r11 build: fixed-base
// softmax (additive K-partials), 2 q-tiles x 2 K-halves per block, XCD
// swizzle, all loads FM, CTX2 FM out, scalar mask flag. VGPR 64, occ 33%,
// VALUBusy 61% + MfmaUtil 24% -- issue-bound at the exp2/pack floor.
// ---------------------------------------------------------------------------
__global__ __launch_bounds__(256) void k_attn(const u16* __restrict__ QLF,
                                              const u16* __restrict__ KF,
                                              const u16* __restrict__ VF,
                                              const int* __restrict__ mask,
                                              const int* __restrict__ flag,
                                              u16* __restrict__ CTX2) {
  __shared__ float pacc[2][64][17];
  __shared__ float pl[2][64];
  __shared__ u32 cls[64][17];
  int tid = threadIdx.x;
  int wave = tid >> 6, l = tid & 63, lo = l & 31, hi = l >> 5;
  int blk = blockIdx.x;
  int xcd = blk & 7, slot = blk >> 3;
  int bh = xcd * 8 + (slot >> 5);
  int qpair = slot & 31;
  int qi = wave & 1;
  int khalf = wave >> 1;
  int qt = qpair * 2 + qi;
  int b = bh >> 4, h = bh & 15;

  const u16* qp = QLF + (size_t)bh * 65536 + (size_t)qt * 1024 + l * 8;
  bf16x8 qb0 = *(const bf16x8*)(qp);
  bf16x8 qb1 = *(const bf16x8*)(qp + 512);

  size_t fbase = (size_t)bh * 65536 + (size_t)khalf * 32768 + l * 8;
  const u16* kp = KF + fbase;
  const u16* vp = VF + fbase;

  f32x16 acc = {};
  float l_run = 0.f;

  if (flag[0]) {
#pragma unroll 1
    for (int kt = 0; kt < 32; ++kt) {
      bf16x8 ka0 = *(const bf16x8*)(kp);
      bf16x8 ka1 = *(const bf16x8*)(kp + 512);
      kp += 1024;
      f32x16 sc = {};
      sc = MFMA(ka0, qb0, sc, 0, 0, 0);
      sc = MFMA(ka1, qb1, sc, 0, 0, 0);
      bf16x8 va0 = *(const bf16x8*)(vp);
      bf16x8 va1 = *(const bf16x8*)(vp + 512);
      vp += 1024;
      union { bf16x8 v; u32 u[4]; } fa;
      float a0 = __builtin_amdgcn_exp2f(sc[0]);
      float a1 = __builtin_amdgcn_exp2f(sc[1]);
      float a2 = __builtin_amdgcn_exp2f(sc[2]);
      float a3 = __builtin_amdgcn_exp2f(sc[3]);
      fa.u[0] = cvtpk(a0, a1);
      fa.u[1] = cvtpk(a2, a3);
      float t0 = (a0 + a1) + (a2 + a3);
      a0 = __builtin_amdgcn_exp2f(sc[4]);
      a1 = __builtin_amdgcn_exp2f(sc[5]);
      a2 = __builtin_amdgcn_exp2f(sc[6]);
      a3 = __builtin_amdgcn_exp2f(sc[7]);
      fa.u[2] = cvtpk(a0, a1);
      fa.u[3] = cvtpk(a2, a3);
      float t1 = (a0 + a1) + (a2 + a3);
      acc = MFMA(va0, fa.v, acc, 0, 0, 0);
      union { bf16x8 v; u32 u[4]; } fc;
      a0 = __builtin_amdgcn_exp2f(sc[8]);
      a1 = __builtin_amdgcn_exp2f(sc[9]);
      a2 = __builtin_amdgcn_exp2f(sc[10]);
      a3 = __builtin_amdgcn_exp2f(sc[11]);
      fc.u[0] = cvtpk(a0, a1);
      fc.u[1] = cvtpk(a2, a3);
      float t2 = (a0 + a1) + (a2 + a3);
      a0 = __builtin_amdgcn_exp2f(sc[12]);
      a1 = __builtin_amdgcn_exp2f(sc[13]);
      a2 = __builtin_amdgcn_exp2f(sc[14]);
      a3 = __builtin_amdgcn_exp2f(sc[15]);
      fc.u[2] = cvtpk(a0, a1);
      fc.u[3] = cvtpk(a2, a3);
      float t3 = (a0 + a1) + (a2 + a3);
      acc = MFMA(va1, fc.v, acc, 0, 0, 0);
      l_run += (t0 + t1) + (t2 + t3);
    }
  } else {
    const int* mp = mask + b * 2048 + khalf * 1024 + lo;
#pragma unroll 1
    for (int kt = 0; kt < 32; ++kt) {
      unsigned long long bm = __ballot(mp[0] != 0);
      mp += 32;
      bf16x8 ka0 = *(const bf16x8*)(kp);
      bf16x8 ka1 = *(const bf16x8*)(kp + 512);
      kp += 1024;
      f32x16 sc = {};
      sc = MFMA(ka0, qb0, sc, 0, 0, 0);
      sc = MFMA(ka1, qb1, sc, 0, 0, 0);
      u32 km = (u32)bm;
#pragma unroll
      for (int i = 0; i < 16; ++i) {
        int key = (i & 3) + 8 * (i >> 2) + 4 * hi;
        if (!((km >> key) & 1)) sc[i] = -3.0e38f;
      }
      bf16x8 va0 = *(const bf16x8*)(vp);
      bf16x8 va1 = *(const bf16x8*)(vp + 512);
      vp += 1024;
      union { bf16x8 v; u32 u[4]; } fa;
      float a0 = __builtin_amdgcn_exp2f(sc[0]);
      float a1 = __builtin_amdgcn_exp2f(sc[1]);
      float a2 = __builtin_amdgcn_exp2f(sc[2]);
      float a3 = __builtin_amdgcn_exp2f(sc[3]);
      fa.u[0] = cvtpk(a0, a1);
      fa.u[1] = cvtpk(a2, a3);
      float t0 = (a0 + a1) + (a2 + a3);
      a0 = __builtin_amdgcn_exp2f(sc[4]);
      a1 = __builtin_amdgcn_exp2f(sc[5]);
      a2 = __builtin_amdgcn_exp2f(sc[6]);
      a3 = __builtin_amdgcn_exp2f(sc[7]);
      fa.u[2] = cvtpk(a0, a1);
      fa.u[3] = cvtpk(a2, a3);
      float t1 = (a0 + a1) + (a2 + a3);
      acc = MFMA(va0, fa.v, acc, 0, 0, 0);
      union { bf16x8 v; u32 u[4]; } fc;
      a0 = __builtin_amdgcn_exp2f(sc[8]);
      a1 = __builtin_amdgcn_exp2f(sc[9]);
      a2 = __builtin_amdgcn_exp2f(sc[10]);
      a3 = __builtin_amdgcn_exp2f(sc[11]);
      fc.u[0] = cvtpk(a0, a1);
      fc.u[1] = cvtpk(a2, a3);
      float t2 = (a0 + a1) + (a2 + a3);
      a0 = __builtin_amdgcn_exp2f(sc[12]);
      a1 = __builtin_amdgcn_exp2f(sc[13]);
      a2 = __builtin_amdgcn_exp2f(sc[14]);
      a3 = __builtin_amdgcn_exp2f(sc[15]);
      fc.u[2] = cvtpk(a0, a1);
      fc.u[3] = cvtpk(a2, a3);
      float t3 = (a0 + a1) + (a2 + a3);
      acc = MFMA(va1, fc.v, acc, 0, 0, 0);
      l_run += (t0 + t1) + (t2 + t3);
    }
  }

  if (khalf) {
#pragma unroll
    for (int i = 0; i < 16; ++i) pacc[qi][l][i] = acc[i];
    pl[qi][l] = l_run;
  }
  __syncthreads();
  if (!khalf) {
#pragma unroll
    for (int i = 0; i < 16; ++i) acc[i] += pacc[qi][l][i];
    l_run += pl[qi][l];
    l_run = xhalf_sum(l_run);
    float inv = 1.0f / l_run;
    int qloc = qi * 32 + lo;
#pragma unroll
    for (int g2 = 0; g2 < 4; ++g2) {
      cls[qloc][g2 * 4 + 2 * hi] = cvtpk(acc[4 * g2 + 0] * inv, acc[4 * g2 + 1] * inv);
      cls[qloc][g2 * 4 + 2 * hi + 1] = cvtpk(acc[4 * g2 + 2] * inv, acc[4 * g2 + 3] * inv);
    }
  }
  __syncthreads();
  int st2 = tid >> 7, kcl = (tid >> 6) & 1, lw = tid & 63;
  const u32* src = &cls[st2 * 32 + (lw & 31)][kcl * 8 + (lw >> 5) * 4];
  uint4 v0;
  v0.x = src[0]; v0.y = src[1]; v0.z = src[2]; v0.w = src[3];
  *(uint4*)(CTX2 + (size_t)(b * 64 + qpair * 2 + st2) * 16384 +
            (2 * h + kcl) * 512 + lw * 8) = v0;
}

// ---------------------------------------------------------------------------
// K5a: ylow = ctx @ WOT^T. CTX2/WOTF fragment-major; 512 thr, 8 waves split
// hr (4 kchunks each), LDS reduce, YLF FM out.
// ---------------------------------------------------------------------------
__global__ __launch_bounds__(512) void k_epi1(const u16* __restrict__ CTX2,
                                              const u16* __restrict__ WOTF,
                                              u16* __restrict__ YLF) {
  __shared__ float red[8][32][33];
  int tid = threadIdx.x;
  int w = tid >> 6, l = tid & 63, lo = l & 31, hi = l >> 5;
  int stile = blockIdx.x;
  const u16* cp = CTX2 + (size_t)stile * 16384 + (4 * w) * 512 + l * 8;
  const u16* wp = WOTF + (4 * w) * 512 + l * 8;
  f32x16 acc = {};
  for (int st = 0; st < 4; ++st) {
    bf16x8 a = *(const bf16x8*)(cp);
    bf16x8 bb = *(const bf16x8*)(wp);
    cp += 512;
    wp += 512;
    acc = MFMA(a, bb, acc, 0, 0, 0);
  }
#pragma unroll
  for (int i = 0; i < 16; ++i)
    red[w][(i & 3) + 8 * (i >> 2) + 4 * hi][lo] = acc[i];
  __syncthreads();
  int m = tid >> 4, c = (tid & 15) * 2;
  float v0 = 0.f, v1 = 0.f;
#pragma unroll
  for (int ww = 0; ww < 8; ++ww) {
    v0 += red[ww][m][c + 0];
    v1 += red[ww][m][c + 1];
  }
  *(u32*)(YLF + (size_t)stile * 1024 + fmoff(m, c)) = cvtpk(v0, v1);
}

// ---------------------------------------------------------------------------
// K5b: out = ylow @ out_v + out_b. YLF/OVF fragment-major -> coalesced.
// Block = 32 s x 128 d (4 waves, one 32-d subtile each), LDS-staged stores.
// ---------------------------------------------------------------------------
__global__ __launch_bounds__(256) void k_epi2(const u16* __restrict__ YLF,
                                              const u16* __restrict__ OVF,
                                              const float* __restrict__ out_b,
                                              float* __restrict__ out) {
  __shared__ float ol[32][133];
  int tid = threadIdx.x;
  int w = tid >> 6, l = tid & 63, lo = l & 31, hi = l >> 5;
  int blk = blockIdx.x;  // 256 s-tiles x 8 d-tiles
  int stile = blk >> 3;
  int s0 = stile * 32;
  int d0 = (blk & 7) * 128;
  int dtile = (blk & 7) * 4 + w;
  const u16* ap = OVF + (size_t)dtile * 1024 + l * 8;
  bf16x8 a0 = *(const bf16x8*)(ap), a1 = *(const bf16x8*)(ap + 512);
  const u16* bp = YLF + (size_t)stile * 1024 + l * 8;
  bf16x8 b0 = *(const bf16x8*)(bp), b1 = *(const bf16x8*)(bp + 512);
  f32x16 acc = {};
  acc = MFMA(a0, b0, acc, 0, 0, 0);
  acc = MFMA(a1, b1, acc, 0, 0, 0);
#pragma unroll
  for (int i = 0; i < 16; ++i)
    ol[lo][w * 32 + (i & 3) + 8 * (i >> 2) + 4 * hi] = acc[i];
  __syncthreads();
  for (int u = tid; u < 1024; u += 256) {
    int s = u >> 5, c = (u & 31) * 4;
    float4 ob = *(const float4*)(out_b + d0 + c);
    float4 o;
    o.x = ol[s][c + 0] + ob.x;
    o.y = ol[s][c + 1] + ob.y;
    o.z = ol[s][c + 2] + ob.z;
    o.w = ol[s][c + 3] + ob.w;
    *(float4*)(out + (size_t)(s0 + s) * 1024 + d0 + c) = o;
  }
}

extern "C" void kernel_launch(void* const* d_in, const int* in_sizes, int n_in,
                              void* d_out, int out_size, void* d_ws, size_t ws_size,
                              hipStream_t stream) {
  const float* x = (const float*)d_in[0];
  const int* mask = (const int*)d_in[1];
  const float* qkv_u = (const float*)d_in[2];
  const float* qkv_v = (const float*)d_in[3];
  const float* qkv_b = (const float*)d_in[4];
  const float* u_attn = (const float*)d_in[5];
  const float* v_attn = (const float*)d_in[6];
  const float* out_u = (const float*)d_in[7];
  const float* out_v = (const float*)d_in[8];
  const float* out_b = (const float*)d_in[9];
  float* out = (float*)d_out;

  char* w = (char*)d_ws;
  u16* WQF = (u16*)(w + 0);                // 32 KB
  u16* WKF = (u16*)(w + (32 << 10));       // 32 KB
  u16* WVF = (u16*)(w + (64 << 10));       // 32 KB
  float* BQ = (float*)(w + (96 << 10));    // 6 KB
  int* FLAG = (int*)(w + (102 << 10));     // 4 B
  u16* WOTF = (u16*)(w + (104 << 10));     // 32 KB
  u16* UTF = (u16*)(w + (136 << 10));      // 64 KB
  u16* OVF = (u16*)(w + (200 << 10));      // 64 KB
  u16* TF = (u16*)(w + (1 << 20));         // 512 KB bf16 FM [256 stiles]
  u16* QLF = (u16*)(w + (2 << 20));        // 8 MB bf16 FM [bh][qt][kc]
  u16* KF = (u16*)(w + (10 << 20));        // 8 MB bf16 FM [bh][tile]
  u16* VF = (u16*)(w + (18 << 20));        // 8 MB bf16 FM [bh][tile] (tau)
  u16* CTX2 = (u16*)(w + (26 << 20));      // 8 MB bf16 FM [256 stiles][32 kc]
  u16* YLF = (u16*)(w + (34 << 20));       // 512 KB bf16 FM [256 stiles]

  k_prep<<<33, 256, 0, stream>>>(qkv_v, qkv_b, u_attn, v_attn, out_u, qkv_u, out_v,
                                 mask, WQF, WKF, WVF, BQ, WOTF, UTF, OVF, FLAG);
  k_proj<<<256, 512, 0, stream>>>(x, UTF, TF);
  k_lowproj<<<1024, 256, 0, stream>>>(TF, WQF, WKF, WVF, BQ, QLF, KF, VF);
  k_attn<<<2048, 256, 0, stream>>>(QLF, KF, VF, mask, FLAG, CTX2);
  k_epi1<<<256, 512, 0, stream>>>(CTX2, WOTF, YLF);
  k_epi2<<<2048, 256, 0, stream>>>(YLF, OVF, out_b, out);
}